// Round 9
// baseline (451.765 us; speedup 1.0000x reference)
//
#include <hip/hip_runtime.h>
#include <hip/hip_bf16.h>

#define N_NODES   20000
#define N_EDGES   100000
#define N_REL     1000
#define F_DIM     128
#define N_HEAD    4
#define HC        512      // N_HEAD * F_DIM
#define HC2       256      // HC/2 (bf16 pairs)
#define N_LAYERS  4
#define REL_EXT_ROWS 1008  // 1000 relations + 1 mean row
#define NEG_SLOPE 0.2f
#define PROJ_NODE_X 79     // node M-chunks of 256 rows (79*256 = 20224 >= 20000)

typedef __attribute__((ext_vector_type(8))) short short8;
typedef __attribute__((ext_vector_type(4))) float floatx4;

__device__ __forceinline__ float loadIn(const void* p, size_t i, int f32) {
    if (f32) return ((const float*)p)[i];
    union { unsigned int u; float f; } c;
    c.u = ((unsigned int)((const unsigned short*)p)[i]) << 16;
    return c.f;
}

__device__ __forceinline__ unsigned short f2bf(float v) {
    __hip_bfloat16 b = __float2bfloat16(v);
    return *(unsigned short*)&b;
}

__device__ __forceinline__ void unpack2(unsigned int u, float& lo, float& hi) {
    union { unsigned int u; float f; } a, b;
    a.u = u << 16;
    b.u = u & 0xFFFF0000u;
    lo = a.f; hi = b.f;
}

__device__ __forceinline__ void unpack8(uint4 v, float* f) {
    unpack2(v.x, f[0], f[1]);
    unpack2(v.y, f[2], f[3]);
    unpack2(v.z, f[4], f[5]);
    unpack2(v.w, f[6], f[7]);
}

// Async global->LDS DMA, 16B per lane. NO destination VGPR -> the register
// allocator cannot serialize a burst of these (the failure mode of r0-r7's
// register gathers). Source address is per-lane; LDS dest is wave-uniform
// base + lane*16 (linear; here loff = 4*lane uints = 16B*lane, so source and
// dest lane-mappings agree). Completion tracked by vmcnt.
__device__ __forceinline__ void gload_lds16(const unsigned int* g, unsigned int* l) {
    __builtin_amdgcn_global_load_lds(
        (const __attribute__((address_space(1))) unsigned int*)g,
        (__attribute__((address_space(3))) unsigned int*)l,
        16, 0, 0);
}

// Drain all outstanding VMEM (incl. global_load_lds), then fence the scheduler
// so no consumer is hoisted above the wait (rule #18).
__device__ __forceinline__ void vm_drain() {
    asm volatile("s_waitcnt vmcnt(0)" ::: "memory");
    __builtin_amdgcn_sched_barrier(0);
}

// ---------------- dtype detection ----------------
__global__ void detect_kernel(const unsigned short* __restrict__ x, int* __restrict__ flag) {
    int t = threadIdx.x;  // 64
    int cnt = 0;
    for (int j = t; j < 256; j += 64) {
        int e = (x[j] >> 7) & 0xFF;
        if (e >= 143) cnt++;
    }
    for (int off = 32; off; off >>= 1) cnt += __shfl_xor(cnt, off);
    if (t == 0) flag[0] = (cnt >= 8) ? 1 : 0;
}

// ---------------- preprocessing ----------------

__global__ void hist_kernel(const int* __restrict__ dst, const int* __restrict__ rel,
                            int* __restrict__ deg, int* __restrict__ rcount) {
    int e = blockIdx.x * 256 + threadIdx.x;
    if (e < N_EDGES) {
        atomicAdd(&deg[dst[e]], 1);
        atomicAdd(&rcount[rel[e]], 1);
    }
}

__global__ void ea_mean_kernel(const int* __restrict__ rcount,
                               const void* __restrict__ relations,
                               float* __restrict__ ea_mean, const int* __restrict__ flag) {
    int f32 = flag[0];
    int b = blockIdx.x;
    int t = threadIdx.x;
    int col = t & 127;
    int rhalf = t >> 7;
    float acc = 0.f;
    for (int j = 0; j < 4; ++j) {
        int r = b * 8 + j * 2 + rhalf;
        acc += (float)rcount[r] * loadIn(relations, (size_t)r * F_DIM + col, f32);
    }
    __shared__ float part[256];
    part[t] = acc;
    __syncthreads();
    if (t < 128)
        atomicAdd(&ea_mean[col], (part[t] + part[t + 128]) * (1.f / (float)N_EDGES));
}

__global__ void relext_kernel(const void* __restrict__ relations,
                              const float* __restrict__ ea_mean,
                              unsigned short* __restrict__ rel_ext, const int* __restrict__ flag) {
    int idx = blockIdx.x * 256 + threadIdx.x;
    if (idx >= REL_EXT_ROWS * F_DIM) return;
    int f32 = flag[0];
    int r = idx >> 7;
    int c = idx & 127;
    float v;
    if (r < N_REL)       v = loadIn(relations, idx, f32);
    else if (r == N_REL) v = ea_mean[c];
    else                 v = 0.f;
    rel_ext[idx] = f2bf(v);
}

__global__ void scan_kernel(const int* __restrict__ deg,
                            int* __restrict__ row_start, int* __restrict__ cursor) {
    __shared__ int part[1024];
    int t = threadIdx.x;
    const int CH = (N_NODES + 1023) / 1024;  // 20
    int base = t * CH;
    int sum = 0;
    for (int j = 0; j < CH; ++j) {
        int idx = base + j;
        if (idx < N_NODES) sum += deg[idx];
    }
    part[t] = sum;
    __syncthreads();
    for (int off = 1; off < 1024; off <<= 1) {
        int u = (t >= off) ? part[t - off] : 0;
        __syncthreads();
        part[t] += u;
        __syncthreads();
    }
    int run = part[t] - sum;
    for (int j = 0; j < CH; ++j) {
        int idx = base + j;
        if (idx < N_NODES) {
            row_start[idx] = run;
            cursor[idx] = run;
            run += deg[idx];
        }
    }
    if (t == 1023) row_start[N_NODES] = part[1023];
}

__global__ void scatter_kernel(const int* __restrict__ src, const int* __restrict__ dst,
                               const int* __restrict__ rel, int* __restrict__ cursor,
                               int* __restrict__ csr_pack) {
    int e = blockIdx.x * 256 + threadIdx.x;
    if (e < N_EDGES) {
        int d = dst[e];
        int p = atomicAdd(&cursor[d], 1);
        csr_pack[p] = src[e] | (rel[e] << 16);
    }
}

// Build inline-8 headers: csr8[i] = { row_start | min(deg,4095)<<17, edge0..edge6 }.
__global__ void build8_kernel(const int* __restrict__ row_start,
                              const int* __restrict__ csr_pack,
                              int* __restrict__ csr8) {
    int i = blockIdx.x * 256 + threadIdx.x;
    if (i >= N_NODES) return;
    int rs = row_start[i];
    int deg = row_start[i + 1] - rs;
    if (deg < 0) deg = 0;
    int dcap = deg > 4095 ? 4095 : deg;
    csr8[i * 8] = rs | (dcap << 17);
    #pragma unroll
    for (int k = 0; k < 7; ++k)
        csr8[i * 8 + 1 + k] = (k < deg) ? csr_pack[rs + k] : 0;
}

__global__ void tail_kernel(const void* __restrict__ relations, void* __restrict__ out,
                            const int* __restrict__ flag) {
    int i = blockIdx.x * 256 + threadIdx.x;
    if (i >= N_REL * F_DIM) return;
    int f32 = flag[0];
    float v = loadIn(relations, i, f32);
    size_t o = (size_t)N_NODES * F_DIM + i;
    if (f32) ((float*)out)[o] = v;
    else     ((unsigned short*)out)[o] = f2bf(v);
}

// ---------------- weight transpose: W[l][128 k][512 n] -> Wt[mat][512 n][128 k] bf16 ----------------
__global__ void w_transpose_kernel(const void* __restrict__ Wl, const void* __restrict__ Wr,
                                   const void* __restrict__ We,
                                   unsigned short* __restrict__ Wt, const int* __restrict__ flag) {
    int f32 = flag[0];
    int k0 = blockIdx.x * 64;
    int n0 = blockIdx.y * 64;
    int mat = blockIdx.z;
    const void* src = (mat < 4) ? Wl : (mat < 8 ? Wr : We);
    size_t base = (size_t)(mat & 3) * F_DIM * HC;
    unsigned short* dst = Wt + (size_t)mat * HC * F_DIM;
    __shared__ float T[64][65];
    int t = threadIdx.x;
    int r = t >> 2, cq = t & 3;
    for (int j = 0; j < 16; ++j) {
        int n = cq * 16 + j;
        T[n][r] = loadIn(src, base + (size_t)(k0 + r) * HC + n0 + n, f32);
    }
    __syncthreads();
    for (int j = 0; j < 16; ++j) {
        int k = cq * 16 + j;
        dst[(size_t)(n0 + r) * F_DIM + k0 + k] = f2bf(T[r][k]);
    }
}

// ---------------- persistent-B streaming projection GEMM ----------------
// r8: 256-row node blocks (4 tiles/block, was 2). Grid (79+2, 8) = 648 blocks
// at 3 blocks/CU -> the WHOLE grid is co-resident: the per-block prologue
// (16KB B-slice load into 64 VGPR/wave) is paid once instead of ~5x serially
// per CU. proj was ~50us/layer at 5% MFMA / 0.9 TB/s -> pure latency/structure.
__launch_bounds__(256, 3)
__global__ void proj_kernel(const void* __restrict__ A_node, int a_input,
                            const unsigned short* __restrict__ rel_ext,
                            const unsigned short* __restrict__ Wlt,
                            const unsigned short* __restrict__ Wrt,
                            const unsigned short* __restrict__ Wet,
                            const void* __restrict__ bl, const void* __restrict__ br,
                            size_t boff,
                            unsigned short* __restrict__ xl,
                            unsigned short* __restrict__ xr,
                            unsigned short* __restrict__ re,
                            const int* __restrict__ flag) {
    __shared__ __align__(16) short As[64][136];   // 17.4 KB (pad: conflict-free ds_read_b128)
    __shared__ __align__(16) short Cs[64 * 136];  // 17.4 KB epilogue transpose
    int f32 = flag[0];
    int t = threadIdx.x;
    int y = blockIdx.y;
    int isNode = (blockIdx.x < PROJ_NODE_X);

    const void* A;
    const unsigned short* Wt;
    const void* bias;
    unsigned short* out;
    int M, mbase, nT, a_f32;
    int n0 = (y & 3) * 128;
    if (isNode) {
        A = A_node; M = N_NODES; nT = 4;
        mbase = blockIdx.x * 256;
        a_f32 = a_input ? f32 : 0;
        if (y < 4) { Wt = Wlt; bias = bl; out = xl; }
        else       { Wt = Wrt; bias = br; out = xr; }
    } else {
        A = (const void*)rel_ext; M = REL_EXT_ROWS; nT = 4;
        int rowchunk = (blockIdx.x - PROJ_NODE_X) * 2 + (y >> 2);
        mbase = rowchunk * 256;
        a_f32 = 0;
        Wt = Wet; bias = nullptr; out = re;
    }

    int wave = t >> 6, lane = t & 63;
    int wm = (wave >> 1) * 32, wn = (wave & 1) * 64;
    int r16 = lane & 15, quad = lane >> 4;

    // -------- pin B slice in registers: 16 x short8 = 64 VGPR --------
    short8 breg[2][2][4];
    #pragma unroll
    for (int half = 0; half < 2; ++half)
        #pragma unroll
        for (int kk = 0; kk < 2; ++kk)
            #pragma unroll
            for (int ni = 0; ni < 4; ++ni)
                breg[half][kk][ni] = *(const short8*)(
                    Wt + (size_t)(n0 + wn + ni * 16 + r16) * F_DIM + half * 64 + kk * 32 + quad * 8);

    // -------- hoisted bias per output column --------
    float bv[4];
    #pragma unroll
    for (int ni = 0; ni < 4; ++ni)
        bv[ni] = bias ? loadIn(bias, boff + n0 + wn + ni * 16 + r16, f32) : 0.f;

    // -------- prologue: load first A tile into regs --------
    short8 aS[4];
    #pragma unroll
    for (int j = 0; j < 4; ++j) {
        int c = t + j * 256;
        int row = c >> 4;
        int colc = (c & 15) * 8;
        int gm = mbase + row;
        short8 v = (short8){0, 0, 0, 0, 0, 0, 0, 0};
        if (gm < M) {
            size_t idx = (size_t)gm * F_DIM + colc;
            if (a_f32) {
                const float* Af = (const float*)A;
                for (int q = 0; q < 8; ++q) v[q] = (short)f2bf(Af[idx + q]);
            } else {
                v = *(const short8*)((const unsigned short*)A + idx);
            }
        }
        aS[j] = v;
    }

    for (int ct = 0; ct < nT; ++ct) {
        int m0 = mbase + ct * 64;
        __syncthreads();   // As writable (prev MFMA ds_reads done) / Cs stores done
        #pragma unroll
        for (int j = 0; j < 4; ++j) {
            int c = t + j * 256;
            *(short8*)&As[c >> 4][(c & 15) * 8] = aS[j];
        }
        // issue next tile's A loads (in flight during MFMA + epilogue + store)
        short8 aN[4];
        if (ct + 1 < nT) {
            int mb = mbase + (ct + 1) * 64;
            #pragma unroll
            for (int j = 0; j < 4; ++j) {
                int c = t + j * 256;
                int row = c >> 4;
                int colc = (c & 15) * 8;
                int gm = mb + row;
                short8 v = (short8){0, 0, 0, 0, 0, 0, 0, 0};
                if (gm < M) {
                    size_t idx = (size_t)gm * F_DIM + colc;
                    if (a_f32) {
                        const float* Af = (const float*)A;
                        for (int q = 0; q < 8; ++q) v[q] = (short)f2bf(Af[idx + q]);
                    } else {
                        v = *(const short8*)((const unsigned short*)A + idx);
                    }
                }
                aN[j] = v;
            }
            #pragma unroll
            for (int j = 0; j < 4; ++j) aS[j] = aN[j];
        }
        __syncthreads();   // As ready

        floatx4 acc[2][4];
        #pragma unroll
        for (int mi = 0; mi < 2; ++mi)
            #pragma unroll
            for (int ni = 0; ni < 4; ++ni)
                acc[mi][ni] = (floatx4){0.f, 0.f, 0.f, 0.f};

        #pragma unroll
        for (int half = 0; half < 2; ++half) {
            #pragma unroll
            for (int kk = 0; kk < 2; ++kk) {
                short8 a[2];
                #pragma unroll
                for (int mi = 0; mi < 2; ++mi)
                    a[mi] = *(const short8*)&As[wm + mi * 16 + r16][half * 64 + kk * 32 + quad * 8];
                #pragma unroll
                for (int mi = 0; mi < 2; ++mi)
                    #pragma unroll
                    for (int ni = 0; ni < 4; ++ni)
                        acc[mi][ni] = __builtin_amdgcn_mfma_f32_16x16x32_bf16(
                            a[mi], breg[half][kk][ni], acc[mi][ni], 0, 0, 0);
            }
        }

        // epilogue: acc -> Cs (bf16, transposed layout for coalesced store)
        #pragma unroll
        for (int mi = 0; mi < 2; ++mi) {
            #pragma unroll
            for (int ni = 0; ni < 4; ++ni) {
                int col = wn + ni * 16 + r16;
                #pragma unroll
                for (int r = 0; r < 4; ++r) {
                    int rowl = wm + mi * 16 + quad * 4 + r;
                    Cs[rowl * 136 + col] = (short)f2bf(acc[mi][ni][r] + bv[ni]);
                }
            }
        }
        __syncthreads();   // Cs ready
        #pragma unroll
        for (int j = 0; j < 4; ++j) {
            int c = t + j * 256;
            int rowl = c >> 4;
            int colc = (c & 15) * 8;
            int gm = m0 + rowl;
            if (gm < M)
                *(short8*)(out + (size_t)gm * HC + n0 + colc) =
                    *(const short8*)&Cs[rowl * 136 + colc];
        }
    }
}

// ---------------- edge kernel: async global_load_lds burst gathers ----------------
// One wave per node; lane l = h*16+q owns channels q*8..q*8+7 of head h. r8 KEY
// CHANGE: the <=7 edge-row pairs are staged via global_load_lds (async DMA, NO
// result VGPRs) -> the register allocator CANNOT serialize the burst (the r0-r7
// failure: every register-gather phrasing collapsed to ~1 outstanding load/wave).
// 14 x 1KB transfers in flight per wave, tracked by vmcnt. Plain per-node loads
// are issued BEFORE the burst so their in-order vmcnt waits don't drain it; the
// self-loop computes while the DMA flies; one vmcnt(0)+sched_barrier, then consume
// from LDS (lane reads its own 16B back: 2-way bank alias = free).
__launch_bounds__(128)
__global__ void edge_kernel(const unsigned int* __restrict__ xl2,
                            const unsigned int* __restrict__ xr2,
                            const unsigned int* __restrict__ re2,
                            const int* __restrict__ csr8,
                            const int* __restrict__ csr_pack,
                            const void* __restrict__ att, size_t att_off,
                            const void* __restrict__ bias, size_t bias_off,
                            void* __restrict__ hout, int final_layer,
                            const int* __restrict__ flag) {
    __shared__ __align__(16) unsigned int stage[2][7][2][256];  // 28,672 B
    int f32 = flag[0];
    int wid = threadIdx.x >> 6;
    int lane = threadIdx.x & 63;
    int i = blockIdx.x * 2 + wid;
    if (i >= N_NODES) return;
    int h = lane >> 4;
    int q = lane & 15;
    int loff = h * 64 + q * 4;   // uint offset within a node's HC2=256-uint row

    // header: broadcast vector loads (same address across wave -> 1 line)
    uint4 h0 = *(const uint4*)(csr8 + (size_t)i * 8);
    uint4 h1 = *(const uint4*)(csr8 + (size_t)i * 8 + 4);
    int rs  = (int)(h0.x & 0x1FFFF);
    int deg = (int)(h0.x >> 17) & 0xFFF;
    int ew[7] = { (int)h0.y, (int)h0.z, (int)h0.w, (int)h1.x, (int)h1.y, (int)h1.z, (int)h1.w };

    // plain per-node loads FIRST (their waits are vmcnt-ordered before the burst)
    uint4 xrv = *(const uint4*)(xr2 + (size_t)i * HC2 + loff);
    uint4 erv = *(const uint4*)(re2 + (size_t)N_REL * HC2 + loff);
    uint4 xsv = *(const uint4*)(xl2 + (size_t)i * HC2 + loff);
    float av[8];
    #pragma unroll
    for (int j = 0; j < 8; ++j)
        av[j] = loadIn(att, att_off + (size_t)h * F_DIM + q * 8 + j, f32);

    // ---- async burst: up to 14 global_load_lds in flight (wave-uniform guard) ----
    int nIn = deg > 7 ? 7 : deg;
    #pragma unroll
    for (int k = 0; k < 7; ++k) {
        if (k < nIn) {
            int pk = ew[k];
            int sn = pk & 0xFFFF;        if (sn >= N_NODES) sn = 0;
            int rn = (pk >> 16) & 0x3FF; if (rn > N_REL) rn = N_REL;
            gload_lds16(xl2 + (size_t)sn * HC2 + loff, &stage[wid][k][0][0]);
            gload_lds16(re2 + (size_t)rn * HC2 + loff, &stage[wid][k][1][0]);
        }
    }

    float xr[8], er[8];
    unpack8(xrv, xr);
    unpack8(erv, er);

    float acc[8];
    float s;
    // self-loop seed (computes while the DMA burst is in flight)
    {
        float xs[8];
        unpack8(xsv, xs);
        float part = 0.f;
        #pragma unroll
        for (int j = 0; j < 8; ++j) {
            float u = xs[j] + xr[j] + er[j];
            u = fmaxf(u, NEG_SLOPE * u);
            part = fmaf(u, av[j], part);
        }
        #pragma unroll
        for (int off = 8; off; off >>= 1) part += __shfl_xor(part, off);
        part = fminf(fmaxf(part, -60.f), 60.f);
        float p = __expf(part);
        s = p;
        #pragma unroll
        for (int j = 0; j < 8; ++j) acc[j] = p * xs[j];
    }

    vm_drain();   // all DMA landed in LDS

    // consume inline edges from LDS (wave-uniform guard)
    #pragma unroll
    for (int k = 0; k < 7; ++k) {
        if (k < nIn) {
            float xlv[8], ee[8];
            uint4 xv = *(const uint4*)&stage[wid][k][0][lane * 4];
            uint4 rv = *(const uint4*)&stage[wid][k][1][lane * 4];
            unpack8(xv, xlv);
            unpack8(rv, ee);
            float part = 0.f;
            #pragma unroll
            for (int j = 0; j < 8; ++j) {
                float u = xlv[j] + xr[j] + ee[j];
                u = fmaxf(u, NEG_SLOPE * u);
                part = fmaf(u, av[j], part);
            }
            #pragma unroll
            for (int off = 8; off; off >>= 1) part += __shfl_xor(part, off);
            part = fminf(fmaxf(part, -60.f), 60.f);
            float pp = __expf(part);
            s += pp;
            #pragma unroll
            for (int j = 0; j < 8; ++j) acc[j] = fmaf(pp, xlv[j], acc[j]);
        }
    }

    // overflow edges (deg > 7, ~13% of nodes): plain batches of 4, wave-uniform
    if (deg > 7) {
        int e1 = rs + deg;
        if (e1 > N_EDGES) e1 = N_EDGES;
        for (int b = rs + 7; b < e1; b += 4) {
            int nb = e1 - b; if (nb > 4) nb = 4;
            uint4 xo[4], ro[4];
            #pragma unroll
            for (int k = 0; k < 4; ++k) {
                if (k < nb) {
                    int pk = csr_pack[b + k];
                    int sn = pk & 0xFFFF;        if (sn >= N_NODES) sn = 0;
                    int rn = (pk >> 16) & 0x3FF; if (rn > N_REL) rn = N_REL;
                    xo[k] = *(const uint4*)(xl2 + (size_t)sn * HC2 + loff);
                    ro[k] = *(const uint4*)(re2 + (size_t)rn * HC2 + loff);
                }
            }
            #pragma unroll
            for (int k = 0; k < 4; ++k) {
                if (k < nb) {
                    float xlv[8], ee[8];
                    unpack8(xo[k], xlv);
                    unpack8(ro[k], ee);
                    float part = 0.f;
                    #pragma unroll
                    for (int j = 0; j < 8; ++j) {
                        float u = xlv[j] + xr[j] + ee[j];
                        u = fmaxf(u, NEG_SLOPE * u);
                        part = fmaf(u, av[j], part);
                    }
                    #pragma unroll
                    for (int off = 8; off; off >>= 1) part += __shfl_xor(part, off);
                    part = fminf(fmaxf(part, -60.f), 60.f);
                    float pp = __expf(part);
                    s += pp;
                    #pragma unroll
                    for (int j = 0; j < 8; ++j) acc[j] = fmaf(pp, xlv[j], acc[j]);
                }
            }
        }
    }

    // normalize own head, then sum across the 4 head groups (lanes differ in bits 4,5)
    float inv = 1.f / s;
    float outv[8];
    #pragma unroll
    for (int j = 0; j < 8; ++j) outv[j] = acc[j] * inv;
    #pragma unroll
    for (int j = 0; j < 8; ++j) {
        outv[j] += __shfl_xor(outv[j], 16);
        outv[j] += __shfl_xor(outv[j], 32);
    }

    if (h == 0) {
        float bv[8];
        #pragma unroll
        for (int j = 0; j < 8; ++j)
            bv[j] = loadIn(bias, bias_off + q * 8 + j, f32);
        size_t o = (size_t)i * F_DIM + q * 8;
        if (final_layer && f32) {
            float* op = (float*)hout + o;
            float4 lo, hi;
            lo.x = outv[0] * 0.25f + bv[0];
            lo.y = outv[1] * 0.25f + bv[1];
            lo.z = outv[2] * 0.25f + bv[2];
            lo.w = outv[3] * 0.25f + bv[3];
            hi.x = outv[4] * 0.25f + bv[4];
            hi.y = outv[5] * 0.25f + bv[5];
            hi.z = outv[6] * 0.25f + bv[6];
            hi.w = outv[7] * 0.25f + bv[7];
            *(float4*)op = lo;
            *(float4*)(op + 4) = hi;
        } else {
            unsigned int w[4];
            #pragma unroll
            for (int p = 0; p < 4; ++p) {
                float v0 = outv[2 * p] * 0.25f + bv[2 * p];
                float v1 = outv[2 * p + 1] * 0.25f + bv[2 * p + 1];
                w[p] = (unsigned int)f2bf(v0) | ((unsigned int)f2bf(v1) << 16);
            }
            *(uint4*)((unsigned short*)hout + o) = *(uint4*)w;
        }
    }
}

// ---------------- launch ----------------

extern "C" void kernel_launch(void* const* d_in, const int* in_sizes, int n_in,
                              void* d_out, int out_size, void* d_ws, size_t ws_size,
                              hipStream_t stream) {
    const void* x          = d_in[0];
    const int*  edge_index = (const int*)d_in[1];
    const void* relations  = d_in[2];
    const int*  rel_index  = (const int*)d_in[3];
    const void* Wl         = d_in[4];
    const void* bl         = d_in[5];
    const void* Wr         = d_in[6];
    const void* br         = d_in[7];
    const void* We         = d_in[8];
    const void* att        = d_in[9];
    const void* bias       = d_in[10];

    char* ws = (char*)d_ws;
    size_t off = 0;
    auto alloc = [&](size_t bytes) -> void* {
        void* p = ws + off;
        off = (off + bytes + 255) & ~(size_t)255;
        return p;
    };
    int*            flag     = (int*)alloc(4);
    // deg / rcount / ea_mean contiguous -> single memset covers all three
    char*           zero0    = ws + off;
    int*            deg      = (int*)alloc(N_NODES * 4);
    int*            rcount   = (int*)alloc(N_REL * 4);
    float*          ea_mean  = (float*)alloc(F_DIM * 4);
    size_t          zlen     = (size_t)((ws + off) - zero0);
    int*            row_start= (int*)alloc((N_NODES + 1) * 4);
    int*            cursor   = (int*)alloc(N_NODES * 4);
    int*            csr_pack = (int*)alloc(N_EDGES * 4);
    int*            csr8     = (int*)alloc((size_t)N_NODES * 8 * 4);  // 640 KB
    unsigned short* rel_ext  = (unsigned short*)alloc((size_t)REL_EXT_ROWS * F_DIM * 2);
    unsigned short* Wt       = (unsigned short*)alloc((size_t)12 * HC * F_DIM * 2);  // 1.57 MB
    unsigned short* re       = (unsigned short*)alloc((size_t)REL_EXT_ROWS * HC * 2);
    unsigned short* hbuf     = (unsigned short*)alloc((size_t)N_NODES * F_DIM * 2);
    unsigned short* xl       = (unsigned short*)alloc((size_t)N_NODES * HC * 2);
    unsigned short* xr       = (unsigned short*)alloc((size_t)N_NODES * HC * 2);
    // total ~50 MB

    const int* esrc = edge_index;
    const int* edst = edge_index + N_EDGES;

    detect_kernel<<<1, 64, 0, stream>>>((const unsigned short*)x, flag);
    hipMemsetAsync(zero0, 0, zlen, stream);
    hist_kernel<<<(N_EDGES + 255) / 256, 256, 0, stream>>>(edst, rel_index, deg, rcount);
    ea_mean_kernel<<<N_REL / 8, 256, 0, stream>>>(rcount, relations, ea_mean, flag);
    relext_kernel<<<(REL_EXT_ROWS * F_DIM + 255) / 256, 256, 0, stream>>>(relations, ea_mean, rel_ext, flag);
    scan_kernel<<<1, 1024, 0, stream>>>(deg, row_start, cursor);
    scatter_kernel<<<(N_EDGES + 255) / 256, 256, 0, stream>>>(esrc, edst, rel_index, cursor, csr_pack);
    build8_kernel<<<(N_NODES + 255) / 256, 256, 0, stream>>>(row_start, csr_pack, csr8);
    w_transpose_kernel<<<dim3(2, 8, 12), 256, 0, stream>>>(Wl, Wr, We, Wt, flag);
    tail_kernel<<<(N_REL * F_DIM + 255) / 256, 256, 0, stream>>>(relations, d_out, flag);

    const void* hin = x;
    int a_input = 1;
    for (int l = 0; l < N_LAYERS; ++l) {
        const unsigned short* Wlt = Wt + (size_t)l * HC * F_DIM;
        const unsigned short* Wrt = Wt + (size_t)(4 + l) * HC * F_DIM;
        const unsigned short* Wet = Wt + (size_t)(8 + l) * HC * F_DIM;
        // persistent-B streaming projection: (79 node + 2 rel) x 8 blocks, all co-resident
        proj_kernel<<<dim3(PROJ_NODE_X + 2, 8), 256, 0, stream>>>(
            hin, a_input, rel_ext, Wlt, Wrt, Wet,
            bl, br, (size_t)l * HC,
            xl, xr, re, flag);
        int final_layer = (l == N_LAYERS - 1);
        void* hout = final_layer ? d_out : (void*)hbuf;
        edge_kernel<<<(N_NODES + 1) / 2, 128, 0, stream>>>(
            (const unsigned int*)xl, (const unsigned int*)xr, (const unsigned int*)re,
            csr8, csr_pack,
            att, (size_t)l * N_HEAD * F_DIM,
            bias, (size_t)l * F_DIM,
            hout, final_layer, flag);
        hin = hbuf;
        a_input = 0;
    }
}

// Round 10
// 405.423 us; speedup vs baseline: 1.1143x; 1.1143x over previous
//
#include <hip/hip_runtime.h>
#include <hip/hip_bf16.h>

#define N_NODES   20000
#define N_EDGES   100000
#define N_REL     1000
#define F_DIM     128
#define N_HEAD    4
#define HC        512      // N_HEAD * F_DIM
#define HC2       256      // HC/2 (bf16 pairs)
#define N_LAYERS  4
#define REL_EXT_ROWS 1008  // 1000 relations + 1 mean row
#define NEG_SLOPE 0.2f
#define PROJ_NODE_X 79     // node M-chunks of 256 rows (79*256 = 20224 >= 20000)

typedef __attribute__((ext_vector_type(8))) short short8;
typedef __attribute__((ext_vector_type(4))) float floatx4;

__device__ __forceinline__ float loadIn(const void* p, size_t i, int f32) {
    if (f32) return ((const float*)p)[i];
    union { unsigned int u; float f; } c;
    c.u = ((unsigned int)((const unsigned short*)p)[i]) << 16;
    return c.f;
}

__device__ __forceinline__ unsigned short f2bf(float v) {
    __hip_bfloat16 b = __float2bfloat16(v);
    return *(unsigned short*)&b;
}

__device__ __forceinline__ void unpack2(unsigned int u, float& lo, float& hi) {
    union { unsigned int u; float f; } a, b;
    a.u = u << 16;
    b.u = u & 0xFFFF0000u;
    lo = a.f; hi = b.f;
}

__device__ __forceinline__ void unpack8(uint4 v, float* f) {
    unpack2(v.x, f[0], f[1]);
    unpack2(v.y, f[2], f[3]);
    unpack2(v.z, f[4], f[5]);
    unpack2(v.w, f[6], f[7]);
}

// Async global->LDS DMA, 16B per lane. Dest = wave-uniform base + lane*16 (our
// thread->chunk map satisfies this exactly). Completion tracked by vmcnt.
__device__ __forceinline__ void gload_lds16(const unsigned short* g, short* l) {
    __builtin_amdgcn_global_load_lds(
        (const __attribute__((address_space(1))) unsigned int*)g,
        (__attribute__((address_space(3))) unsigned int*)l,
        16, 0, 0);
}

// ---------------- dtype detection ----------------
__global__ void detect_kernel(const unsigned short* __restrict__ x, int* __restrict__ flag) {
    int t = threadIdx.x;  // 64
    int cnt = 0;
    for (int j = t; j < 256; j += 64) {
        int e = (x[j] >> 7) & 0xFF;
        if (e >= 143) cnt++;
    }
    for (int off = 32; off; off >>= 1) cnt += __shfl_xor(cnt, off);
    if (t == 0) flag[0] = (cnt >= 8) ? 1 : 0;
}

// x -> bf16 once (kills layer-0 scalar-f32 staging path in proj)
__global__ void xcast_kernel(const void* __restrict__ x, unsigned short* __restrict__ xbf,
                             const int* __restrict__ flag) {
    int idx = blockIdx.x * 256 + threadIdx.x;   // one per 4 elems
    if (idx >= N_NODES * F_DIM / 4) return;
    int f32 = flag[0];
    uint2 o;
    if (f32) {
        float4 v = ((const float4*)x)[idx];
        o.x = (unsigned int)f2bf(v.x) | ((unsigned int)f2bf(v.y) << 16);
        o.y = (unsigned int)f2bf(v.z) | ((unsigned int)f2bf(v.w) << 16);
    } else {
        o = ((const uint2*)x)[idx];
    }
    ((uint2*)xbf)[idx] = o;
}

// ---------------- preprocessing ----------------

__global__ void hist_kernel(const int* __restrict__ dst, const int* __restrict__ rel,
                            int* __restrict__ deg, int* __restrict__ rcount) {
    int e = blockIdx.x * 256 + threadIdx.x;
    if (e < N_EDGES) {
        atomicAdd(&deg[dst[e]], 1);
        atomicAdd(&rcount[rel[e]], 1);
    }
}

__global__ void ea_mean_kernel(const int* __restrict__ rcount,
                               const void* __restrict__ relations,
                               float* __restrict__ ea_mean, const int* __restrict__ flag) {
    int f32 = flag[0];
    int b = blockIdx.x;
    int t = threadIdx.x;
    int col = t & 127;
    int rhalf = t >> 7;
    float acc = 0.f;
    for (int j = 0; j < 4; ++j) {
        int r = b * 8 + j * 2 + rhalf;
        acc += (float)rcount[r] * loadIn(relations, (size_t)r * F_DIM + col, f32);
    }
    __shared__ float part[256];
    part[t] = acc;
    __syncthreads();
    if (t < 128)
        atomicAdd(&ea_mean[col], (part[t] + part[t + 128]) * (1.f / (float)N_EDGES));
}

__global__ void relext_kernel(const void* __restrict__ relations,
                              const float* __restrict__ ea_mean,
                              unsigned short* __restrict__ rel_ext, const int* __restrict__ flag) {
    int idx = blockIdx.x * 256 + threadIdx.x;
    if (idx >= REL_EXT_ROWS * F_DIM) return;
    int f32 = flag[0];
    int r = idx >> 7;
    int c = idx & 127;
    float v;
    if (r < N_REL)       v = loadIn(relations, idx, f32);
    else if (r == N_REL) v = ea_mean[c];
    else                 v = 0.f;
    rel_ext[idx] = f2bf(v);
}

__global__ void scan_kernel(const int* __restrict__ deg,
                            int* __restrict__ row_start, int* __restrict__ cursor) {
    __shared__ int part[1024];
    int t = threadIdx.x;
    const int CH = (N_NODES + 1023) / 1024;  // 20
    int base = t * CH;
    int sum = 0;
    for (int j = 0; j < CH; ++j) {
        int idx = base + j;
        if (idx < N_NODES) sum += deg[idx];
    }
    part[t] = sum;
    __syncthreads();
    for (int off = 1; off < 1024; off <<= 1) {
        int u = (t >= off) ? part[t - off] : 0;
        __syncthreads();
        part[t] += u;
        __syncthreads();
    }
    int run = part[t] - sum;
    for (int j = 0; j < CH; ++j) {
        int idx = base + j;
        if (idx < N_NODES) {
            row_start[idx] = run;
            cursor[idx] = run;
            run += deg[idx];
        }
    }
    if (t == 1023) row_start[N_NODES] = part[1023];
}

__global__ void scatter_kernel(const int* __restrict__ src, const int* __restrict__ dst,
                               const int* __restrict__ rel, int* __restrict__ cursor,
                               int* __restrict__ csr_pack) {
    int e = blockIdx.x * 256 + threadIdx.x;
    if (e < N_EDGES) {
        int d = dst[e];
        int p = atomicAdd(&cursor[d], 1);
        csr_pack[p] = src[e] | (rel[e] << 16);
    }
}

// Build inline-8 headers: csr8[i] = { row_start | min(deg,4095)<<17, edge0..edge6 }.
__global__ void build8_kernel(const int* __restrict__ row_start,
                              const int* __restrict__ csr_pack,
                              int* __restrict__ csr8) {
    int i = blockIdx.x * 256 + threadIdx.x;
    if (i >= N_NODES) return;
    int rs = row_start[i];
    int deg = row_start[i + 1] - rs;
    if (deg < 0) deg = 0;
    int dcap = deg > 4095 ? 4095 : deg;
    csr8[i * 8] = rs | (dcap << 17);
    #pragma unroll
    for (int k = 0; k < 7; ++k)
        csr8[i * 8 + 1 + k] = (k < deg) ? csr_pack[rs + k] : 0;
}

__global__ void tail_kernel(const void* __restrict__ relations, void* __restrict__ out,
                            const int* __restrict__ flag) {
    int i = blockIdx.x * 256 + threadIdx.x;
    if (i >= N_REL * F_DIM) return;
    int f32 = flag[0];
    float v = loadIn(relations, i, f32);
    size_t o = (size_t)N_NODES * F_DIM + i;
    if (f32) ((float*)out)[o] = v;
    else     ((unsigned short*)out)[o] = f2bf(v);
}

// ---------------- weight transpose: W[l][128 k][512 n] -> Wt[mat][512 n][128 k] bf16 ----------------
__global__ void w_transpose_kernel(const void* __restrict__ Wl, const void* __restrict__ Wr,
                                   const void* __restrict__ We,
                                   unsigned short* __restrict__ Wt, const int* __restrict__ flag) {
    int f32 = flag[0];
    int k0 = blockIdx.x * 64;
    int n0 = blockIdx.y * 64;
    int mat = blockIdx.z;
    const void* src = (mat < 4) ? Wl : (mat < 8 ? Wr : We);
    size_t base = (size_t)(mat & 3) * F_DIM * HC;
    unsigned short* dst = Wt + (size_t)mat * HC * F_DIM;
    __shared__ float T[64][65];
    int t = threadIdx.x;
    int r = t >> 2, cq = t & 3;
    for (int j = 0; j < 16; ++j) {
        int n = cq * 16 + j;
        T[n][r] = loadIn(src, base + (size_t)(k0 + r) * HC + n0 + n, f32);
    }
    __syncthreads();
    for (int j = 0; j < 16; ++j) {
        int k = cq * 16 + j;
        dst[(size_t)(n0 + r) * F_DIM + k0 + k] = f2bf(T[r][k]);
    }
}

// ---------------- proj: persistent-B + async-DMA double-buffered A (m97 pattern) ----------------
// A staged via global_load_lds into unpadded As[2][64*128] (16KB/tile) — async DMA has no
// dest VGPRs, so the next tile's staging genuinely flies UNDER the 32-MFMA+epilogue phase
// (register-staged prefetch was always serialized by the compiler — r0-r9 lesson).
// Bank conflicts on the MFMA a-fragment reads (unpadded row stride 256B => 16-way) fixed by
// the both-sides swizzle (rule #21): physical chunk = logical chunk ^ (row&15), applied to
// the pre-swizzled GLOBAL source at staging and to the ds_read address => <=2-way (free).
// Raw s_barriers with counted waits: lgkmcnt(0) before barrier-1 (Cs/As LDS ops drained,
// DMA untouched); vmcnt(4) before barrier-2 (4 gloads retired, 4 stores still in flight —
// stores are exec-unconditional via address clamp so per-wave vmem counts are fixed).
__launch_bounds__(256, 3)
__global__ void proj_kernel(const unsigned short* __restrict__ A_node,
                            const unsigned short* __restrict__ rel_ext,
                            const unsigned short* __restrict__ Wlt,
                            const unsigned short* __restrict__ Wrt,
                            const unsigned short* __restrict__ Wet,
                            const void* __restrict__ bl, const void* __restrict__ br,
                            size_t boff,
                            unsigned short* __restrict__ xl,
                            unsigned short* __restrict__ xr,
                            unsigned short* __restrict__ re,
                            const int* __restrict__ flag) {
    __shared__ __align__(16) short As[2][64 * 128];   // 2 x 16 KB, swizzled chunk layout
    __shared__ __align__(16) short Cs[64 * 136];      // 17.4 KB epilogue transpose
    int f32 = flag[0];
    int t = threadIdx.x;
    int y = blockIdx.y;
    int isNode = (blockIdx.x < PROJ_NODE_X);

    const unsigned short* A;
    const unsigned short* Wt;
    const void* bias;
    unsigned short* out;
    int M, mbase;
    int n0 = (y & 3) * 128;
    if (isNode) {
        A = A_node; M = N_NODES;
        mbase = blockIdx.x * 256;
        if (y < 4) { Wt = Wlt; bias = bl; out = xl; }
        else       { Wt = Wrt; bias = br; out = xr; }
    } else {
        A = rel_ext; M = REL_EXT_ROWS;
        int rowchunk = (blockIdx.x - PROJ_NODE_X) * 2 + (y >> 2);
        mbase = rowchunk * 256;
        Wt = Wet; bias = nullptr; out = re;
    }
    const int nT = 4;

    int wave = t >> 6, lane = t & 63;
    int wm = (wave >> 1) * 32, wn = (wave & 1) * 64;
    int r16 = lane & 15, quad = lane >> 4;

    // -------- pin B slice in registers: 16 x short8 = 64 VGPR --------
    short8 breg[2][2][4];
    #pragma unroll
    for (int half = 0; half < 2; ++half)
        #pragma unroll
        for (int kk = 0; kk < 2; ++kk)
            #pragma unroll
            for (int ni = 0; ni < 4; ++ni)
                breg[half][kk][ni] = *(const short8*)(
                    Wt + (size_t)(n0 + wn + ni * 16 + r16) * F_DIM + half * 64 + kk * 32 + quad * 8);

    float bv[4];
    #pragma unroll
    for (int ni = 0; ni < 4; ++ni)
        bv[ni] = bias ? loadIn(bias, boff + n0 + wn + ni * 16 + r16, f32) : 0.f;

    // stage one 64-row tile into As[buf]: thread chunk c = t + j*256; dest = c*16B
    // (wave-uniform base + lane*16 ✓); source pre-swizzled: logical chunk = (c&15)^(row&15).
    auto STAGE = [&](int buf, int ct2) {
        int base = mbase + ct2 * 64;
        #pragma unroll
        for (int j = 0; j < 4; ++j) {
            int c = t + j * 256;
            int row = c >> 4, ch = c & 15;
            int gm = base + row;
            if (gm >= M) gm = M - 1;                 // clamp: duplicate row, discarded later
            int sch = ch ^ (row & 15);
            gload_lds16(A + (size_t)gm * F_DIM + sch * 8, &As[buf][c * 8]);
        }
    };

    STAGE(0, 0);
    asm volatile("s_waitcnt vmcnt(0)" ::: "memory");
    __builtin_amdgcn_sched_barrier(0);
    __syncthreads();

    int cur = 0;
    for (int ct = 0; ct < nT; ++ct) {
        int m0 = mbase + ct * 64;
        if (ct + 1 < nT) STAGE(cur ^ 1, ct + 1);     // async DMA flies under MFMA+epilogue
        __builtin_amdgcn_sched_barrier(0);           // keep DMA issue ahead of compute

        floatx4 acc[2][4];
        #pragma unroll
        for (int mi = 0; mi < 2; ++mi)
            #pragma unroll
            for (int ni = 0; ni < 4; ++ni)
                acc[mi][ni] = (floatx4){0.f, 0.f, 0.f, 0.f};

        #pragma unroll
        for (int half = 0; half < 2; ++half) {
            #pragma unroll
            for (int kk = 0; kk < 2; ++kk) {
                short8 a[2];
                #pragma unroll
                for (int mi = 0; mi < 2; ++mi) {
                    int row = wm + mi * 16 + r16;
                    int pch = (half * 8 + kk * 4 + quad) ^ (row & 15);   // swizzled read
                    a[mi] = *(const short8*)&As[cur][row * 128 + pch * 8];
                }
                #pragma unroll
                for (int mi = 0; mi < 2; ++mi)
                    #pragma unroll
                    for (int ni = 0; ni < 4; ++ni)
                        acc[mi][ni] = __builtin_amdgcn_mfma_f32_16x16x32_bf16(
                            a[mi], breg[half][kk][ni], acc[mi][ni], 0, 0, 0);
            }
        }

        // epilogue: acc -> Cs (bf16, transposed layout for coalesced store)
        #pragma unroll
        for (int mi = 0; mi < 2; ++mi) {
            #pragma unroll
            for (int ni = 0; ni < 4; ++ni) {
                int col = wn + ni * 16 + r16;
                #pragma unroll
                for (int r = 0; r < 4; ++r) {
                    int rowl = wm + mi * 16 + quad * 4 + r;
                    Cs[rowl * 136 + col] = (short)f2bf(acc[mi][ni][r] + bv[ni]);
                }
            }
        }
        asm volatile("s_waitcnt lgkmcnt(0)" ::: "memory");  // Cs writes + As[cur] reads done
        __builtin_amdgcn_s_barrier();                       // DMA deliberately NOT drained

        // store Cs -> global: exec-unconditional (clamped address writes duplicate of the
        // clamped row's correct data) so per-wave vmem counts stay fixed for vmcnt(4).
        #pragma unroll
        for (int j = 0; j < 4; ++j) {
            int c = t + j * 256;
            int rowl = c >> 4;
            int colc = (c & 15) * 8;
            int gm = m0 + rowl;
            if (gm >= M) gm = M - 1;
            *(short8*)(out + (size_t)gm * HC + n0 + colc) =
                *(const short8*)&Cs[rowl * 136 + colc];
        }
        if (ct + 1 < nT) {
            asm volatile("s_waitcnt vmcnt(4)" ::: "memory");  // 4 gloads retired; stores fly
            __builtin_amdgcn_sched_barrier(0);
        }
        __builtin_amdgcn_s_barrier();                // As[cur^1] published; Cs consumed
        cur ^= 1;
    }
}

// ---------------- edge kernel: r3-best (inline-8 CSR, guarded burst; 45.8-47.0 us) ----------------
// r9 established the floor: aggregate random-1KB-gather throughput (~5 TB/s) saturates at
// ~2500 waves x 1 outstanding; neither per-wave MLP (async DMA, r9: slower via occupancy)
// nor masked/pinned register bursts (r5-r7: neutral) move it. This is the best variant.
__launch_bounds__(128)
__global__ void edge_kernel(const unsigned int* __restrict__ xl2,
                            const unsigned int* __restrict__ xr2,
                            const unsigned int* __restrict__ re2,
                            const int* __restrict__ csr8,
                            const int* __restrict__ csr_pack,
                            const void* __restrict__ att, size_t att_off,
                            const void* __restrict__ bias, size_t bias_off,
                            void* __restrict__ hout, int final_layer,
                            const int* __restrict__ flag) {
    int f32 = flag[0];
    int wid = threadIdx.x >> 6;
    int lane = threadIdx.x & 63;
    int i = blockIdx.x * 2 + wid;
    if (i >= N_NODES) return;
    int h = lane >> 4;
    int q = lane & 15;
    int loff = h * 64 + q * 4;   // uint offset within a node's HC2=256-uint row

    uint4 h0 = *(const uint4*)(csr8 + (size_t)i * 8);
    uint4 h1 = *(const uint4*)(csr8 + (size_t)i * 8 + 4);
    int rs  = (int)(h0.x & 0x1FFFF);
    int deg = (int)(h0.x >> 17) & 0xFFF;
    int ew[7] = { (int)h0.y, (int)h0.z, (int)h0.w, (int)h1.x, (int)h1.y, (int)h1.z, (int)h1.w };

    float xr[8];
    { uint4 v = *(const uint4*)(xr2 + (size_t)i * HC2 + loff); unpack8(v, xr); }
    float er[8];
    { uint4 v = *(const uint4*)(re2 + (size_t)N_REL * HC2 + loff); unpack8(v, er); }
    float av[8];
    #pragma unroll
    for (int j = 0; j < 8; ++j)
        av[j] = loadIn(att, att_off + (size_t)h * F_DIM + q * 8 + j, f32);

    int nIn = deg > 7 ? 7 : deg;
    uint4 xv[7], rv[7];
    #pragma unroll
    for (int k = 0; k < 7; ++k) {
        if (k < nIn) {
            int pk = ew[k];
            int sn = pk & 0xFFFF;        if (sn >= N_NODES) sn = 0;
            int rn = (pk >> 16) & 0x3FF; if (rn > N_REL) rn = N_REL;
            xv[k] = *(const uint4*)(xl2 + (size_t)sn * HC2 + loff);
            rv[k] = *(const uint4*)(re2 + (size_t)rn * HC2 + loff);
        }
    }

    float acc[8];
    float s;
    {
        float xs[8];
        uint4 v = *(const uint4*)(xl2 + (size_t)i * HC2 + loff);
        unpack8(v, xs);
        float part = 0.f;
        #pragma unroll
        for (int j = 0; j < 8; ++j) {
            float u = xs[j] + xr[j] + er[j];
            u = fmaxf(u, NEG_SLOPE * u);
            part = fmaf(u, av[j], part);
        }
        #pragma unroll
        for (int off = 8; off; off >>= 1) part += __shfl_xor(part, off);
        part = fminf(fmaxf(part, -60.f), 60.f);
        float p = __expf(part);
        s = p;
        #pragma unroll
        for (int j = 0; j < 8; ++j) acc[j] = p * xs[j];
    }

    #pragma unroll
    for (int k = 0; k < 7; ++k) {
        if (k < nIn) {
            float xlv[8], ee[8];
            unpack8(xv[k], xlv);
            unpack8(rv[k], ee);
            float part = 0.f;
            #pragma unroll
            for (int j = 0; j < 8; ++j) {
                float u = xlv[j] + xr[j] + ee[j];
                u = fmaxf(u, NEG_SLOPE * u);
                part = fmaf(u, av[j], part);
            }
            #pragma unroll
            for (int off = 8; off; off >>= 1) part += __shfl_xor(part, off);
            part = fminf(fmaxf(part, -60.f), 60.f);
            float pp = __expf(part);
            s += pp;
            #pragma unroll
            for (int j = 0; j < 8; ++j) acc[j] = fmaf(pp, xlv[j], acc[j]);
        }
    }

    if (deg > 7) {
        int e1 = rs + deg;
        if (e1 > N_EDGES) e1 = N_EDGES;
        for (int b = rs + 7; b < e1; b += 4) {
            int nb = e1 - b; if (nb > 4) nb = 4;
            uint4 xo[4], ro[4];
            #pragma unroll
            for (int k = 0; k < 4; ++k) {
                if (k < nb) {
                    int pk = csr_pack[b + k];
                    int sn = pk & 0xFFFF;        if (sn >= N_NODES) sn = 0;
                    int rn = (pk >> 16) & 0x3FF; if (rn > N_REL) rn = N_REL;
                    xo[k] = *(const uint4*)(xl2 + (size_t)sn * HC2 + loff);
                    ro[k] = *(const uint4*)(re2 + (size_t)rn * HC2 + loff);
                }
            }
            #pragma unroll
            for (int k = 0; k < 4; ++k) {
                if (k < nb) {
                    float xlv[8], ee[8];
                    unpack8(xo[k], xlv);
                    unpack8(ro[k], ee);
                    float part = 0.f;
                    #pragma unroll
                    for (int j = 0; j < 8; ++j) {
                        float u = xlv[j] + xr[j] + ee[j];
                        u = fmaxf(u, NEG_SLOPE * u);
                        part = fmaf(u, av[j], part);
                    }
                    #pragma unroll
                    for (int off = 8; off; off >>= 1) part += __shfl_xor(part, off);
                    part = fminf(fmaxf(part, -60.f), 60.f);
                    float pp = __expf(part);
                    s += pp;
                    #pragma unroll
                    for (int j = 0; j < 8; ++j) acc[j] = fmaf(pp, xlv[j], acc[j]);
                }
            }
        }
    }

    float inv = 1.f / s;
    float outv[8];
    #pragma unroll
    for (int j = 0; j < 8; ++j) outv[j] = acc[j] * inv;
    #pragma unroll
    for (int j = 0; j < 8; ++j) {
        outv[j] += __shfl_xor(outv[j], 16);
        outv[j] += __shfl_xor(outv[j], 32);
    }

    if (h == 0) {
        float bv[8];
        #pragma unroll
        for (int j = 0; j < 8; ++j)
            bv[j] = loadIn(bias, bias_off + q * 8 + j, f32);
        size_t o = (size_t)i * F_DIM + q * 8;
        if (final_layer && f32) {
            float* op = (float*)hout + o;
            float4 lo, hi;
            lo.x = outv[0] * 0.25f + bv[0];
            lo.y = outv[1] * 0.25f + bv[1];
            lo.z = outv[2] * 0.25f + bv[2];
            lo.w = outv[3] * 0.25f + bv[3];
            hi.x = outv[4] * 0.25f + bv[4];
            hi.y = outv[5] * 0.25f + bv[5];
            hi.z = outv[6] * 0.25f + bv[6];
            hi.w = outv[7] * 0.25f + bv[7];
            *(float4*)op = lo;
            *(float4*)(op + 4) = hi;
        } else {
            unsigned int w[4];
            #pragma unroll
            for (int p = 0; p < 4; ++p) {
                float v0 = outv[2 * p] * 0.25f + bv[2 * p];
                float v1 = outv[2 * p + 1] * 0.25f + bv[2 * p + 1];
                w[p] = (unsigned int)f2bf(v0) | ((unsigned int)f2bf(v1) << 16);
            }
            *(uint4*)((unsigned short*)hout + o) = *(uint4*)w;
        }
    }
}

// ---------------- launch ----------------

extern "C" void kernel_launch(void* const* d_in, const int* in_sizes, int n_in,
                              void* d_out, int out_size, void* d_ws, size_t ws_size,
                              hipStream_t stream) {
    const void* x          = d_in[0];
    const int*  edge_index = (const int*)d_in[1];
    const void* relations  = d_in[2];
    const int*  rel_index  = (const int*)d_in[3];
    const void* Wl         = d_in[4];
    const void* bl         = d_in[5];
    const void* Wr         = d_in[6];
    const void* br         = d_in[7];
    const void* We         = d_in[8];
    const void* att        = d_in[9];
    const void* bias       = d_in[10];

    char* ws = (char*)d_ws;
    size_t off = 0;
    auto alloc = [&](size_t bytes) -> void* {
        void* p = ws + off;
        off = (off + bytes + 255) & ~(size_t)255;
        return p;
    };
    int*            flag     = (int*)alloc(4);
    // deg / rcount / ea_mean contiguous -> single memset covers all three
    char*           zero0    = ws + off;
    int*            deg      = (int*)alloc(N_NODES * 4);
    int*            rcount   = (int*)alloc(N_REL * 4);
    float*          ea_mean  = (float*)alloc(F_DIM * 4);
    size_t          zlen     = (size_t)((ws + off) - zero0);
    int*            row_start= (int*)alloc((N_NODES + 1) * 4);
    int*            cursor   = (int*)alloc(N_NODES * 4);
    int*            csr_pack = (int*)alloc(N_EDGES * 4);
    int*            csr8     = (int*)alloc((size_t)N_NODES * 8 * 4);  // 640 KB
    unsigned short* rel_ext  = (unsigned short*)alloc((size_t)REL_EXT_ROWS * F_DIM * 2);
    unsigned short* xbf      = (unsigned short*)alloc((size_t)N_NODES * F_DIM * 2);  // 5.1 MB
    unsigned short* Wt       = (unsigned short*)alloc((size_t)12 * HC * F_DIM * 2);  // 1.57 MB
    unsigned short* re       = (unsigned short*)alloc((size_t)REL_EXT_ROWS * HC * 2);
    unsigned short* hbuf     = (unsigned short*)alloc((size_t)N_NODES * F_DIM * 2);
    unsigned short* xl       = (unsigned short*)alloc((size_t)N_NODES * HC * 2);
    unsigned short* xr       = (unsigned short*)alloc((size_t)N_NODES * HC * 2);
    // total ~55 MB

    const int* esrc = edge_index;
    const int* edst = edge_index + N_EDGES;

    detect_kernel<<<1, 64, 0, stream>>>((const unsigned short*)x, flag);
    hipMemsetAsync(zero0, 0, zlen, stream);
    xcast_kernel<<<(N_NODES * F_DIM / 4 + 255) / 256, 256, 0, stream>>>(x, xbf, flag);
    hist_kernel<<<(N_EDGES + 255) / 256, 256, 0, stream>>>(edst, rel_index, deg, rcount);
    ea_mean_kernel<<<N_REL / 8, 256, 0, stream>>>(rcount, relations, ea_mean, flag);
    relext_kernel<<<(REL_EXT_ROWS * F_DIM + 255) / 256, 256, 0, stream>>>(relations, ea_mean, rel_ext, flag);
    scan_kernel<<<1, 1024, 0, stream>>>(deg, row_start, cursor);
    scatter_kernel<<<(N_EDGES + 255) / 256, 256, 0, stream>>>(esrc, edst, rel_index, cursor, csr_pack);
    build8_kernel<<<(N_NODES + 255) / 256, 256, 0, stream>>>(row_start, csr_pack, csr8);
    w_transpose_kernel<<<dim3(2, 8, 12), 256, 0, stream>>>(Wl, Wr, We, Wt, flag);
    tail_kernel<<<(N_REL * F_DIM + 255) / 256, 256, 0, stream>>>(relations, d_out, flag);

    const unsigned short* hin = xbf;
    for (int l = 0; l < N_LAYERS; ++l) {
        const unsigned short* Wlt = Wt + (size_t)l * HC * F_DIM;
        const unsigned short* Wrt = Wt + (size_t)(4 + l) * HC * F_DIM;
        const unsigned short* Wet = Wt + (size_t)(8 + l) * HC * F_DIM;
        // persistent-B + async-DMA proj: (79 node + 2 rel) x 8 blocks
        proj_kernel<<<dim3(PROJ_NODE_X + 2, 8), 256, 0, stream>>>(
            hin, rel_ext, Wlt, Wrt, Wet,
            bl, br, (size_t)l * HC,
            xl, xr, re, flag);
        int final_layer = (l == N_LAYERS - 1);
        void* hout = final_layer ? d_out : (void*)hbuf;
        edge_kernel<<<(N_NODES + 1) / 2, 128, 0, stream>>>(
            (const unsigned int*)xl, (const unsigned int*)xr, (const unsigned int*)re,
            csr8, csr_pack,
            att, (size_t)l * N_HEAD * F_DIM,
            bias, (size_t)l * F_DIM,
            hout, final_layer, flag);
        hin = hbuf;
    }
}